// Round 2
// baseline (377.826 us; speedup 1.0000x reference)
//
#include <hip/hip_runtime.h>
#include <hip/hip_bf16.h>

typedef __attribute__((ext_vector_type(8))) short bf16x8;
typedef __attribute__((ext_vector_type(4))) float f32x4;

__device__ __forceinline__ short f2b(float x) {
    __hip_bfloat16 h = __float2bfloat16(x);
    short s;
    __builtin_memcpy(&s, &h, 2);
    return s;
}

// ---------------- fp32 -> bf16 convert (vectorized) ----------------
__global__ __launch_bounds__(256) void k_cvt(const float* __restrict__ src,
                                             short* __restrict__ dst, int n4) {
    int i = blockIdx.x * 256 + threadIdx.x;
    if (i >= n4) return;
    float4 v = ((const float4*)src)[i];
    short4 o;
    o.x = f2b(v.x); o.y = f2b(v.y); o.z = f2b(v.z); o.w = f2b(v.w);
    ((short4*)dst)[i] = o;
}

// ---------------- memory rows + zero pads ----------------
__global__ __launch_bounds__(256) void k_aux(const float* __restrict__ mk,
                                             const float* __restrict__ mv,
                                             short* __restrict__ kcat,
                                             short* __restrict__ vcat,
                                             short* __restrict__ vt) {
    int i = blockIdx.x * 256 + threadIdx.x;
    int b = i >> 16;
    int r = (i >> 10) & 63;
    int d = i & 1023;
    kcat[((size_t)(b * 2176 + 2048 + r)) * 1024 + d] = f2b(mk[r * 1024 + d] * 8.0f);
    vcat[((size_t)(b * 2176 + 2048 + r)) * 1024 + d] = f2b(mv[r * 1024 + d] * 8.0f);
    kcat[((size_t)(b * 2176 + 2112 + r)) * 1024 + d] = 0;
    int h = (i >> 12) & 15, dd = (i >> 6) & 63, c = i & 63;
    vt[((size_t)((b * 16 + h) * 64 + dd)) * 2176 + 2112 + c] = 0;
}

// ---------------- bf16 NT GEMM: C[r][o] = sum_k A[r][k]*W[o][k] + bias[o] ----------------
template <int MODE>
__global__ __launch_bounds__(256) void gemm_nt(const short* __restrict__ A,
                                               const short* __restrict__ Bw,
                                               const float* __restrict__ bias,
                                               void* __restrict__ Cout) {
    __shared__ __align__(16) short As[128][40];
    __shared__ __align__(16) short Bs[128][40];
    const int tid = threadIdx.x;
    const int bm = blockIdx.x, bn = blockIdx.y;
    const int w = tid >> 6, lane = tid & 63;
    const int wm = w >> 1, wn = w & 1;
    const int lr = lane & 15, lg = lane >> 4;
    const int srow = tid >> 2, schunk = tid & 3;

    f32x4 acc[4][4] = {};

    for (int k0 = 0; k0 < 1024; k0 += 32) {
        __syncthreads();
        #pragma unroll
        for (int i = 0; i < 2; ++i) {
            int r = srow + i * 64;
            bf16x8 av = *(const bf16x8*)(A + (size_t)(bm * 128 + r) * 1024 + k0 + schunk * 8);
            *(bf16x8*)(&As[r][schunk * 8]) = av;
            bf16x8 bv = *(const bf16x8*)(Bw + (size_t)(bn * 128 + r) * 1024 + k0 + schunk * 8);
            *(bf16x8*)(&Bs[r][schunk * 8]) = bv;
        }
        __syncthreads();
        bf16x8 af[4], bfr[4];
        #pragma unroll
        for (int m = 0; m < 4; ++m) af[m] = *(const bf16x8*)(&As[wm * 64 + m * 16 + lr][lg * 8]);
        #pragma unroll
        for (int n = 0; n < 4; ++n) bfr[n] = *(const bf16x8*)(&Bs[wn * 64 + n * 16 + lr][lg * 8]);
        #pragma unroll
        for (int m = 0; m < 4; ++m)
            #pragma unroll
            for (int n = 0; n < 4; ++n)
                acc[m][n] = __builtin_amdgcn_mfma_f32_16x16x32_bf16(af[m], bfr[n], acc[m][n], 0, 0, 0);
    }

    #pragma unroll
    for (int m = 0; m < 4; ++m) {
        #pragma unroll
        for (int n = 0; n < 4; ++n) {
            int col = bn * 128 + wn * 64 + n * 16 + lr;
            float bv = bias[col];
            #pragma unroll
            for (int r = 0; r < 4; ++r) {
                int row = bm * 128 + wm * 64 + m * 16 + lg * 4 + r;
                float val = acc[m][n][r] + bv;
                if (MODE == 0) {
                    ((short*)Cout)[(size_t)row * 1024 + col] = f2b(val);
                } else if (MODE == 1) {
                    int rr = (row >> 11) * 2176 + (row & 2047);
                    ((short*)Cout)[(size_t)rr * 1024 + col] = f2b(val);
                } else {
                    ((float*)Cout)[(size_t)row * 1024 + col] = val;
                }
            }
        }
    }
}

// ---------------- per-head V transpose ----------------
__global__ __launch_bounds__(256) void k_vtrans(const short* __restrict__ vcat,
                                                short* __restrict__ vt) {
    __shared__ __align__(16) short t[64][72];
    const int kk0 = blockIdx.x * 64, h = blockIdx.y, b = blockIdx.z;
    const int tid = threadIdx.x;
    const int r = tid >> 3, c = tid & 7;
    #pragma unroll
    for (int i = 0; i < 2; ++i) {
        int row = r + i * 32;
        bf16x8 v = *(const bf16x8*)(vcat + ((size_t)(b * 2176 + kk0 + row)) * 1024 + h * 64 + c * 8);
        *(bf16x8*)(&t[row][c * 8]) = v;
    }
    __syncthreads();
    #pragma unroll
    for (int i = 0; i < 2; ++i) {
        int d = r + i * 32;
        bf16x8 outv;
        #pragma unroll
        for (int j = 0; j < 8; ++j) outv[j] = t[c * 8 + j][d];
        *(bf16x8*)(vt + ((size_t)((b * 16 + h) * 64 + d)) * 2176 + kk0 + c * 8) = outv;
    }
}

// ---------------- flash attention: grid (16 qtiles, 16 heads, 2 batch), 8 waves ----------------
// Each wave owns 16 q-rows. 512 threads/block, 2 blocks/CU -> 16 waves/CU (VGPR cap).
__global__ __launch_bounds__(512) void k_attn(const short* __restrict__ qp,
                                              const short* __restrict__ kcat,
                                              const short* __restrict__ vt,
                                              const int* __restrict__ maskI,
                                              short* __restrict__ aout) {
    __shared__ float smask[2176];
    __shared__ __align__(16) short Pt[8][16][136];

    const int qt = blockIdx.x, h = blockIdx.y, b = blockIdx.z;
    const int tid = threadIdx.x;
    const int w = tid >> 6, lane = tid & 63;
    const int lr = lane & 15, lg = lane >> 4;

    for (int i = tid; i < 2176; i += 512) {
        float mval;
        if (i < 2048)       mval = maskI[b * 2048 + i] ? -INFINITY : 0.0f;
        else if (i < 2112)  mval = 0.0f;      // memory slots: never masked
        else                mval = -INFINITY; // tail pad of last key tile
        smask[i] = mval;
    }
    __syncthreads();

    // Q fragments (16 rows per wave) held in registers for the whole kernel
    const size_t qbase = ((size_t)(b * 2048 + qt * 128 + w * 16)) * 1024 + h * 64;
    bf16x8 qf[2];
    #pragma unroll
    for (int ks = 0; ks < 2; ++ks)
        qf[ks] = *(const bf16x8*)(qp + qbase + (size_t)lr * 1024 + ks * 32 + lg * 8);

    float m_run[4], l_run[4];
    f32x4 o[4] = {};
    #pragma unroll
    for (int r = 0; r < 4; ++r) { m_run[r] = -1e30f; l_run[r] = 0.0f; }

    for (int kt = 0; kt < 17; ++kt) {
        const int key0 = kt * 128;
        // S = Q K^T
        f32x4 s[8] = {};
        #pragma unroll
        for (int ks = 0; ks < 2; ++ks) {
            #pragma unroll
            for (int n = 0; n < 8; ++n) {
                bf16x8 kf = *(const bf16x8*)(kcat +
                    ((size_t)(b * 2176 + key0 + n * 16 + lr)) * 1024 + h * 64 + ks * 32 + lg * 8);
                s[n] = __builtin_amdgcn_mfma_f32_16x16x32_bf16(qf[ks], kf, s[n], 0, 0, 0);
            }
        }
        float madd[8];
        #pragma unroll
        for (int n = 0; n < 8; ++n) madd[n] = smask[key0 + n * 16 + lr];

        // online softmax (row stats: reduce over lanes 0..15 of each 16-lane group)
        #pragma unroll
        for (int r = 0; r < 4; ++r) {
            float sv[8];
            float mx = m_run[r];
            #pragma unroll
            for (int n = 0; n < 8; ++n) {
                sv[n] = s[n][r] * 0.125f + madd[n];
                mx = fmaxf(mx, sv[n]);
            }
            #pragma unroll
            for (int off = 1; off < 16; off <<= 1) mx = fmaxf(mx, __shfl_xor(mx, off));
            float corr = __expf(m_run[r] - mx);
            float rs = 0.0f;
            #pragma unroll
            for (int n = 0; n < 8; ++n) {
                float pv = __expf(sv[n] - mx);
                s[n][r] = pv;
                rs += pv;
            }
            #pragma unroll
            for (int off = 1; off < 16; off <<= 1) rs += __shfl_xor(rs, off);
            m_run[r] = mx;
            l_run[r] = l_run[r] * corr + rs;
            #pragma unroll
            for (int nO = 0; nO < 4; ++nO) o[nO][r] *= corr;
        }

        // P (D-layout) -> LDS -> A-fragments. Wave-private rows: no barrier needed.
        #pragma unroll
        for (int n = 0; n < 8; ++n)
            #pragma unroll
            for (int r = 0; r < 4; ++r)
                Pt[w][lg * 4 + r][n * 16 + lr] = f2b(s[n][r]);

        // O += P V
        #pragma unroll
        for (int ks2 = 0; ks2 < 4; ++ks2) {
            bf16x8 pa = *(const bf16x8*)(&Pt[w][lr][ks2 * 32 + lg * 8]);
            #pragma unroll
            for (int nO = 0; nO < 4; ++nO) {
                bf16x8 vf = *(const bf16x8*)(vt +
                    ((size_t)((b * 16 + h) * 64 + nO * 16 + lr)) * 2176 + key0 + ks2 * 32 + lg * 8);
                o[nO] = __builtin_amdgcn_mfma_f32_16x16x32_bf16(pa, vf, o[nO], 0, 0, 0);
            }
        }
    }

    #pragma unroll
    for (int r = 0; r < 4; ++r) {
        float inv = 1.0f / l_run[r];
        int qrow = qt * 128 + w * 16 + lg * 4 + r;
        #pragma unroll
        for (int nO = 0; nO < 4; ++nO)
            aout[((size_t)(b * 2048 + qrow)) * 1024 + h * 64 + nO * 16 + lr] =
                f2b(o[nO][r] * inv);
    }
}

extern "C" void kernel_launch(void* const* d_in, const int* in_sizes, int n_in,
                              void* d_out, int out_size, void* d_ws, size_t ws_size,
                              hipStream_t stream) {
    const float* q  = (const float*)d_in[0];
    const float* k  = (const float*)d_in[1];
    const float* v  = (const float*)d_in[2];
    const int* mask = (const int*)d_in[3];
    const float* Wq = (const float*)d_in[4];
    const float* bq = (const float*)d_in[5];
    const float* Wk = (const float*)d_in[6];
    const float* bk = (const float*)d_in[7];
    const float* Wv = (const float*)d_in[8];
    const float* bv = (const float*)d_in[9];
    const float* Wo = (const float*)d_in[10];
    const float* bo = (const float*)d_in[11];
    const float* mk = (const float*)d_in[12];
    const float* mv = (const float*)d_in[13];

    char* ws = (char*)d_ws;
    size_t off = 0;
    auto alloc = [&](size_t bytes) {
        char* p = ws + off;
        off += (bytes + 255) & ~(size_t)255;
        return p;
    };
    short* qb   = (short*)alloc(4096ull * 1024 * 2);
    short* kb   = (short*)alloc(4096ull * 1024 * 2);
    short* vb   = (short*)alloc(4096ull * 1024 * 2);
    short* Wqb  = (short*)alloc(1024ull * 1024 * 2);
    short* Wkb  = (short*)alloc(1024ull * 1024 * 2);
    short* Wvb  = (short*)alloc(1024ull * 1024 * 2);
    short* Wob  = (short*)alloc(1024ull * 1024 * 2);
    short* qp   = (short*)alloc(4096ull * 1024 * 2);
    short* kcat = (short*)alloc(2ull * 2176 * 1024 * 2);
    short* vcat = (short*)alloc(2ull * 2176 * 1024 * 2);
    short* vtb  = (short*)alloc(2ull * 16 * 64 * 2176 * 2);
    short* aout = (short*)alloc(4096ull * 1024 * 2);

    k_cvt<<<4096, 256, 0, stream>>>(q, qb, 1048576);
    k_cvt<<<4096, 256, 0, stream>>>(k, kb, 1048576);
    k_cvt<<<4096, 256, 0, stream>>>(v, vb, 1048576);
    k_cvt<<<1024, 256, 0, stream>>>(Wq, Wqb, 262144);
    k_cvt<<<1024, 256, 0, stream>>>(Wk, Wkb, 262144);
    k_cvt<<<1024, 256, 0, stream>>>(Wv, Wvb, 262144);
    k_cvt<<<1024, 256, 0, stream>>>(Wo, Wob, 262144);
    k_aux<<<512, 256, 0, stream>>>(mk, mv, kcat, vcat, vtb);

    gemm_nt<0><<<dim3(32, 8), 256, 0, stream>>>(qb, Wqb, bq, qp);
    gemm_nt<1><<<dim3(32, 8), 256, 0, stream>>>(kb, Wkb, bk, kcat);
    gemm_nt<1><<<dim3(32, 8), 256, 0, stream>>>(vb, Wvb, bv, vcat);

    k_vtrans<<<dim3(33, 16, 2), 256, 0, stream>>>(vcat, vtb);

    k_attn<<<dim3(16, 16, 2), 512, 0, stream>>>(qp, kcat, vtb, mask, aout);

    gemm_nt<2><<<dim3(32, 8), 256, 0, stream>>>(aout, Wob, bo, (float*)d_out);
}

// Round 3
// 336.076 us; speedup vs baseline: 1.1242x; 1.1242x over previous
//
#include <hip/hip_runtime.h>
#include <hip/hip_bf16.h>

typedef __attribute__((ext_vector_type(8))) short bf16x8;
typedef __attribute__((ext_vector_type(4))) float f32x4;

__device__ __forceinline__ short f2b(float x) {
    __hip_bfloat16 h = __float2bfloat16(x);
    short s;
    __builtin_memcpy(&s, &h, 2);
    return s;
}

// ---------------- fp32 -> bf16 convert (vectorized) ----------------
__global__ __launch_bounds__(256) void k_cvt(const float* __restrict__ src,
                                             short* __restrict__ dst, int n4) {
    int i = blockIdx.x * 256 + threadIdx.x;
    if (i >= n4) return;
    float4 v = ((const float4*)src)[i];
    short4 o;
    o.x = f2b(v.x); o.y = f2b(v.y); o.z = f2b(v.z); o.w = f2b(v.w);
    ((short4*)dst)[i] = o;
}

// ---------------- memory rows + zero pads ----------------
__global__ __launch_bounds__(256) void k_aux(const float* __restrict__ mk,
                                             const float* __restrict__ mv,
                                             short* __restrict__ kcat,
                                             short* __restrict__ vcat,
                                             short* __restrict__ vt) {
    int i = blockIdx.x * 256 + threadIdx.x;
    int b = i >> 16;
    int r = (i >> 10) & 63;
    int d = i & 1023;
    kcat[((size_t)(b * 2176 + 2048 + r)) * 1024 + d] = f2b(mk[r * 1024 + d] * 8.0f);
    vcat[((size_t)(b * 2176 + 2048 + r)) * 1024 + d] = f2b(mv[r * 1024 + d] * 8.0f);
    kcat[((size_t)(b * 2176 + 2112 + r)) * 1024 + d] = 0;
    int h = (i >> 12) & 15, dd = (i >> 6) & 63, c = i & 63;
    vt[((size_t)((b * 16 + h) * 64 + dd)) * 2176 + 2112 + c] = 0;
}

// ---------------- bf16 NT GEMM: C[r][o] = sum_k A[r][k]*W[o][k] + bias[o] ----------------
template <int MODE>
__global__ __launch_bounds__(256) void gemm_nt(const short* __restrict__ A,
                                               const short* __restrict__ Bw,
                                               const float* __restrict__ bias,
                                               void* __restrict__ Cout) {
    __shared__ __align__(16) short As[128][40];
    __shared__ __align__(16) short Bs[128][40];
    const int tid = threadIdx.x;
    const int bm = blockIdx.x, bn = blockIdx.y;
    const int w = tid >> 6, lane = tid & 63;
    const int wm = w >> 1, wn = w & 1;
    const int lr = lane & 15, lg = lane >> 4;
    const int srow = tid >> 2, schunk = tid & 3;

    f32x4 acc[4][4] = {};

    for (int k0 = 0; k0 < 1024; k0 += 32) {
        __syncthreads();
        #pragma unroll
        for (int i = 0; i < 2; ++i) {
            int r = srow + i * 64;
            bf16x8 av = *(const bf16x8*)(A + (size_t)(bm * 128 + r) * 1024 + k0 + schunk * 8);
            *(bf16x8*)(&As[r][schunk * 8]) = av;
            bf16x8 bv = *(const bf16x8*)(Bw + (size_t)(bn * 128 + r) * 1024 + k0 + schunk * 8);
            *(bf16x8*)(&Bs[r][schunk * 8]) = bv;
        }
        __syncthreads();
        bf16x8 af[4], bfr[4];
        #pragma unroll
        for (int m = 0; m < 4; ++m) af[m] = *(const bf16x8*)(&As[wm * 64 + m * 16 + lr][lg * 8]);
        #pragma unroll
        for (int n = 0; n < 4; ++n) bfr[n] = *(const bf16x8*)(&Bs[wn * 64 + n * 16 + lr][lg * 8]);
        #pragma unroll
        for (int m = 0; m < 4; ++m)
            #pragma unroll
            for (int n = 0; n < 4; ++n)
                acc[m][n] = __builtin_amdgcn_mfma_f32_16x16x32_bf16(af[m], bfr[n], acc[m][n], 0, 0, 0);
    }

    #pragma unroll
    for (int m = 0; m < 4; ++m) {
        #pragma unroll
        for (int n = 0; n < 4; ++n) {
            int col = bn * 128 + wn * 64 + n * 16 + lr;
            float bv = bias[col];
            #pragma unroll
            for (int r = 0; r < 4; ++r) {
                int row = bm * 128 + wm * 64 + m * 16 + lg * 4 + r;
                float val = acc[m][n][r] + bv;
                if (MODE == 0) {
                    ((short*)Cout)[(size_t)row * 1024 + col] = f2b(val);
                } else if (MODE == 1) {
                    int rr = (row >> 11) * 2176 + (row & 2047);
                    ((short*)Cout)[(size_t)rr * 1024 + col] = f2b(val);
                } else {
                    ((float*)Cout)[(size_t)row * 1024 + col] = val;
                }
            }
        }
    }
}

// ---------------- per-head V transpose ----------------
__global__ __launch_bounds__(256) void k_vtrans(const short* __restrict__ vcat,
                                                short* __restrict__ vt) {
    __shared__ __align__(16) short t[64][72];
    const int kk0 = blockIdx.x * 64, h = blockIdx.y, b = blockIdx.z;
    const int tid = threadIdx.x;
    const int r = tid >> 3, c = tid & 7;
    #pragma unroll
    for (int i = 0; i < 2; ++i) {
        int row = r + i * 32;
        bf16x8 v = *(const bf16x8*)(vcat + ((size_t)(b * 2176 + kk0 + row)) * 1024 + h * 64 + c * 8);
        *(bf16x8*)(&t[row][c * 8]) = v;
    }
    __syncthreads();
    #pragma unroll
    for (int i = 0; i < 2; ++i) {
        int d = r + i * 32;
        bf16x8 outv;
        #pragma unroll
        for (int j = 0; j < 8; ++j) outv[j] = t[c * 8 + j][d];
        *(bf16x8*)(vt + ((size_t)((b * 16 + h) * 64 + d)) * 2176 + kk0 + c * 8) = outv;
    }
}

// ---------------- flash attention: 512 blocks (XCD-swizzled), 4 waves, 32 q-rows/wave ----
// XCD swizzle: all 16 q-tiles of one (b,h) panel -> same XCD => K/V panel L2-resident.
// K fragments register-prefetched one tile ahead (no barriers in the loop).
__global__ __launch_bounds__(256) void k_attn(const short* __restrict__ qp,
                                              const short* __restrict__ kcat,
                                              const short* __restrict__ vt,
                                              const int* __restrict__ maskI,
                                              short* __restrict__ aout) {
    __shared__ float smask[2176];
    __shared__ __align__(16) short Pt[4][32][136];

    // bid%8 is the XCD this block dispatches to; pin panel g = bid%8 + 8*((bid>>3)&3)
    const int bid = blockIdx.x;
    const int x = bid & 7, j = bid >> 3;
    const int g = x + 8 * (j & 3);   // panel 0..31 (h + 16*b)
    const int qt = j >> 2;           // 0..15
    const int h = g & 15, b = g >> 4;

    const int tid = threadIdx.x;
    const int w = tid >> 6, lane = tid & 63;
    const int lr = lane & 15, lg = lane >> 4;

    for (int i = tid; i < 2176; i += 256) {
        float mval;
        if (i < 2048)       mval = maskI[b * 2048 + i] ? -INFINITY : 0.0f;
        else if (i < 2112)  mval = 0.0f;      // memory slots: never masked
        else                mval = -INFINITY; // tail pad of last key tile
        smask[i] = mval;
    }
    __syncthreads();

    // Q fragments held in registers for the whole kernel
    const size_t qbase = ((size_t)(b * 2048 + qt * 128 + w * 32)) * 1024 + h * 64;
    bf16x8 qf[2][2];
    #pragma unroll
    for (int m = 0; m < 2; ++m)
        #pragma unroll
        for (int ks = 0; ks < 2; ++ks)
            qf[m][ks] = *(const bf16x8*)(qp + qbase + (size_t)(m * 16 + lr) * 1024 + ks * 32 + lg * 8);

    const short* Kb = kcat + (size_t)b * 2176 * 1024 + h * 64;   // + key*1024 + d-slice
    const short* Vb = vt + ((size_t)(b * 16 + h) * 64) * 2176;   // + d*2176 + key

    float m_run[2][4], l_run[2][4];
    f32x4 o[2][4] = {};
    #pragma unroll
    for (int m = 0; m < 2; ++m)
        #pragma unroll
        for (int r = 0; r < 4; ++r) { m_run[m][r] = -1e30f; l_run[m][r] = 0.0f; }

    // prefetch K tile 0 into registers
    bf16x8 kf[2][8];
    #pragma unroll
    for (int ks = 0; ks < 2; ++ks)
        #pragma unroll
        for (int n = 0; n < 8; ++n)
            kf[ks][n] = *(const bf16x8*)(Kb + (size_t)(n * 16 + lr) * 1024 + ks * 32 + lg * 8);

    for (int kt = 0; kt < 17; ++kt) {
        const int key0 = kt * 128;
        // S = Q K^T (K from prefetched registers)
        f32x4 s[2][8] = {};
        #pragma unroll
        for (int ks = 0; ks < 2; ++ks)
            #pragma unroll
            for (int n = 0; n < 8; ++n) {
                s[0][n] = __builtin_amdgcn_mfma_f32_16x16x32_bf16(qf[0][ks], kf[ks][n], s[0][n], 0, 0, 0);
                s[1][n] = __builtin_amdgcn_mfma_f32_16x16x32_bf16(qf[1][ks], kf[ks][n], s[1][n], 0, 0, 0);
            }

        // issue next tile's K loads now; softmax+Pt+PV (~1.5k cyc) hides the latency
        if (kt < 16) {
            const int nk0 = key0 + 128;
            #pragma unroll
            for (int ks = 0; ks < 2; ++ks)
                #pragma unroll
                for (int n = 0; n < 8; ++n)
                    kf[ks][n] = *(const bf16x8*)(Kb + (size_t)(nk0 + n * 16 + lr) * 1024 + ks * 32 + lg * 8);
        }

        float madd[8];
        #pragma unroll
        for (int n = 0; n < 8; ++n) madd[n] = smask[key0 + n * 16 + lr];

        // online softmax (row stats: reduce over lanes 0..15 of each 16-lane group)
        #pragma unroll
        for (int m = 0; m < 2; ++m) {
            #pragma unroll
            for (int r = 0; r < 4; ++r) {
                float sv[8];
                float mx = m_run[m][r];
                #pragma unroll
                for (int n = 0; n < 8; ++n) {
                    sv[n] = s[m][n][r] * 0.125f + madd[n];
                    mx = fmaxf(mx, sv[n]);
                }
                #pragma unroll
                for (int off = 1; off < 16; off <<= 1) mx = fmaxf(mx, __shfl_xor(mx, off));
                float corr = __expf(m_run[m][r] - mx);
                float rs = 0.0f;
                #pragma unroll
                for (int n = 0; n < 8; ++n) {
                    float pv = __expf(sv[n] - mx);
                    s[m][n][r] = pv;
                    rs += pv;
                }
                #pragma unroll
                for (int off = 1; off < 16; off <<= 1) rs += __shfl_xor(rs, off);
                m_run[m][r] = mx;
                l_run[m][r] = l_run[m][r] * corr + rs;
                #pragma unroll
                for (int nO = 0; nO < 4; ++nO) o[m][nO][r] *= corr;
            }
        }

        // P (D-layout) -> LDS -> A-fragments. Wave-private rows: no barrier needed.
        #pragma unroll
        for (int m = 0; m < 2; ++m)
            #pragma unroll
            for (int n = 0; n < 8; ++n)
                #pragma unroll
                for (int r = 0; r < 4; ++r)
                    Pt[w][m * 16 + lg * 4 + r][n * 16 + lr] = f2b(s[m][n][r]);

        // O += P V  (V loads are L2 hits after XCD swizzle)
        #pragma unroll
        for (int ks2 = 0; ks2 < 4; ++ks2) {
            bf16x8 pa[2];
            pa[0] = *(const bf16x8*)(&Pt[w][lr][ks2 * 32 + lg * 8]);
            pa[1] = *(const bf16x8*)(&Pt[w][16 + lr][ks2 * 32 + lg * 8]);
            #pragma unroll
            for (int nO = 0; nO < 4; ++nO) {
                bf16x8 vf = *(const bf16x8*)(Vb +
                    (size_t)(nO * 16 + lr) * 2176 + key0 + ks2 * 32 + lg * 8);
                o[0][nO] = __builtin_amdgcn_mfma_f32_16x16x32_bf16(pa[0], vf, o[0][nO], 0, 0, 0);
                o[1][nO] = __builtin_amdgcn_mfma_f32_16x16x32_bf16(pa[1], vf, o[1][nO], 0, 0, 0);
            }
        }
    }

    #pragma unroll
    for (int m = 0; m < 2; ++m) {
        #pragma unroll
        for (int r = 0; r < 4; ++r) {
            float inv = 1.0f / l_run[m][r];
            int qrow = qt * 128 + w * 32 + m * 16 + lg * 4 + r;
            #pragma unroll
            for (int nO = 0; nO < 4; ++nO)
                aout[((size_t)(b * 2048 + qrow)) * 1024 + h * 64 + nO * 16 + lr] =
                    f2b(o[m][nO][r] * inv);
        }
    }
}

extern "C" void kernel_launch(void* const* d_in, const int* in_sizes, int n_in,
                              void* d_out, int out_size, void* d_ws, size_t ws_size,
                              hipStream_t stream) {
    const float* q  = (const float*)d_in[0];
    const float* k  = (const float*)d_in[1];
    const float* v  = (const float*)d_in[2];
    const int* mask = (const int*)d_in[3];
    const float* Wq = (const float*)d_in[4];
    const float* bq = (const float*)d_in[5];
    const float* Wk = (const float*)d_in[6];
    const float* bk = (const float*)d_in[7];
    const float* Wv = (const float*)d_in[8];
    const float* bv = (const float*)d_in[9];
    const float* Wo = (const float*)d_in[10];
    const float* bo = (const float*)d_in[11];
    const float* mk = (const float*)d_in[12];
    const float* mv = (const float*)d_in[13];

    char* ws = (char*)d_ws;
    size_t off = 0;
    auto alloc = [&](size_t bytes) {
        char* p = ws + off;
        off += (bytes + 255) & ~(size_t)255;
        return p;
    };
    short* qb   = (short*)alloc(4096ull * 1024 * 2);
    short* kb   = (short*)alloc(4096ull * 1024 * 2);
    short* vb   = (short*)alloc(4096ull * 1024 * 2);
    short* Wqb  = (short*)alloc(1024ull * 1024 * 2);
    short* Wkb  = (short*)alloc(1024ull * 1024 * 2);
    short* Wvb  = (short*)alloc(1024ull * 1024 * 2);
    short* Wob  = (short*)alloc(1024ull * 1024 * 2);
    short* qp   = (short*)alloc(4096ull * 1024 * 2);
    short* kcat = (short*)alloc(2ull * 2176 * 1024 * 2);
    short* vcat = (short*)alloc(2ull * 2176 * 1024 * 2);
    short* vtb  = (short*)alloc(2ull * 16 * 64 * 2176 * 2);
    short* aout = (short*)alloc(4096ull * 1024 * 2);

    k_cvt<<<4096, 256, 0, stream>>>(q, qb, 1048576);
    k_cvt<<<4096, 256, 0, stream>>>(k, kb, 1048576);
    k_cvt<<<4096, 256, 0, stream>>>(v, vb, 1048576);
    k_cvt<<<1024, 256, 0, stream>>>(Wq, Wqb, 262144);
    k_cvt<<<1024, 256, 0, stream>>>(Wk, Wkb, 262144);
    k_cvt<<<1024, 256, 0, stream>>>(Wv, Wvb, 262144);
    k_cvt<<<1024, 256, 0, stream>>>(Wo, Wob, 262144);
    k_aux<<<512, 256, 0, stream>>>(mk, mv, kcat, vcat, vtb);

    gemm_nt<0><<<dim3(32, 8), 256, 0, stream>>>(qb, Wqb, bq, qp);
    gemm_nt<1><<<dim3(32, 8), 256, 0, stream>>>(kb, Wkb, bk, kcat);
    gemm_nt<1><<<dim3(32, 8), 256, 0, stream>>>(vb, Wvb, bv, vcat);

    k_vtrans<<<dim3(33, 16, 2), 256, 0, stream>>>(vcat, vtb);

    k_attn<<<512, 256, 0, stream>>>(qp, kcat, vtb, mask, aout);

    gemm_nt<2><<<dim3(32, 8), 256, 0, stream>>>(aout, Wob, bo, (float*)d_out);
}

// Round 4
// 205.499 us; speedup vs baseline: 1.8386x; 1.6354x over previous
//
#include <hip/hip_runtime.h>
#include <hip/hip_bf16.h>

typedef __attribute__((ext_vector_type(8))) short bf16x8;
typedef __attribute__((ext_vector_type(4))) float f32x4;

__device__ __forceinline__ short f2b(float x) {
    __hip_bfloat16 h = __float2bfloat16(x);
    short s;
    __builtin_memcpy(&s, &h, 2);
    return s;
}

__device__ __forceinline__ void gload16(const short* g, short* l) {
    __builtin_amdgcn_global_load_lds((const __attribute__((address_space(1))) void*)g,
                                     (__attribute__((address_space(3))) void*)l, 16, 0, 0);
}

// ---------------- fp32 -> bf16 convert (vectorized) ----------------
__global__ __launch_bounds__(256) void k_cvt(const float* __restrict__ src,
                                             short* __restrict__ dst, int n4) {
    int i = blockIdx.x * 256 + threadIdx.x;
    if (i >= n4) return;
    float4 v = ((const float4*)src)[i];
    short4 o;
    o.x = f2b(v.x); o.y = f2b(v.y); o.z = f2b(v.z); o.w = f2b(v.w);
    ((short4*)dst)[i] = o;
}

// ---------------- memory rows + zero pads ----------------
__global__ __launch_bounds__(256) void k_aux(const float* __restrict__ mk,
                                             const float* __restrict__ mv,
                                             short* __restrict__ kcat,
                                             short* __restrict__ vcat,
                                             short* __restrict__ vt) {
    int i = blockIdx.x * 256 + threadIdx.x;
    int b = i >> 16;
    int r = (i >> 10) & 63;
    int d = i & 1023;
    kcat[((size_t)(b * 2176 + 2048 + r)) * 1024 + d] = f2b(mk[r * 1024 + d] * 8.0f);
    vcat[((size_t)(b * 2176 + 2048 + r)) * 1024 + d] = f2b(mv[r * 1024 + d] * 8.0f);
    kcat[((size_t)(b * 2176 + 2112 + r)) * 1024 + d] = 0;
    int h = (i >> 12) & 15, dd = (i >> 6) & 63, c = i & 63;
    vt[((size_t)((b * 16 + h) * 64 + dd)) * 2176 + 2112 + c] = 0;
}

// ---------------- bf16 NT GEMM: C[r][o] = sum_k A[r][k]*W[o][k] + bias[o] ----------------
template <int MODE>
__global__ __launch_bounds__(256) void gemm_nt(const short* __restrict__ A,
                                               const short* __restrict__ Bw,
                                               const float* __restrict__ bias,
                                               void* __restrict__ Cout) {
    __shared__ __align__(16) short As[128][40];
    __shared__ __align__(16) short Bs[128][40];
    const int tid = threadIdx.x;
    const int bm = blockIdx.x, bn = blockIdx.y;
    const int w = tid >> 6, lane = tid & 63;
    const int wm = w >> 1, wn = w & 1;
    const int lr = lane & 15, lg = lane >> 4;
    const int srow = tid >> 2, schunk = tid & 3;

    f32x4 acc[4][4] = {};

    for (int k0 = 0; k0 < 1024; k0 += 32) {
        __syncthreads();
        #pragma unroll
        for (int i = 0; i < 2; ++i) {
            int r = srow + i * 64;
            bf16x8 av = *(const bf16x8*)(A + (size_t)(bm * 128 + r) * 1024 + k0 + schunk * 8);
            *(bf16x8*)(&As[r][schunk * 8]) = av;
            bf16x8 bv = *(const bf16x8*)(Bw + (size_t)(bn * 128 + r) * 1024 + k0 + schunk * 8);
            *(bf16x8*)(&Bs[r][schunk * 8]) = bv;
        }
        __syncthreads();
        bf16x8 af[4], bfr[4];
        #pragma unroll
        for (int m = 0; m < 4; ++m) af[m] = *(const bf16x8*)(&As[wm * 64 + m * 16 + lr][lg * 8]);
        #pragma unroll
        for (int n = 0; n < 4; ++n) bfr[n] = *(const bf16x8*)(&Bs[wn * 64 + n * 16 + lr][lg * 8]);
        #pragma unroll
        for (int m = 0; m < 4; ++m)
            #pragma unroll
            for (int n = 0; n < 4; ++n)
                acc[m][n] = __builtin_amdgcn_mfma_f32_16x16x32_bf16(af[m], bfr[n], acc[m][n], 0, 0, 0);
    }

    #pragma unroll
    for (int m = 0; m < 4; ++m) {
        #pragma unroll
        for (int n = 0; n < 4; ++n) {
            int col = bn * 128 + wn * 64 + n * 16 + lr;
            float bv = bias[col];
            #pragma unroll
            for (int r = 0; r < 4; ++r) {
                int row = bm * 128 + wm * 64 + m * 16 + lg * 4 + r;
                float val = acc[m][n][r] + bv;
                if (MODE == 0) {
                    ((short*)Cout)[(size_t)row * 1024 + col] = f2b(val);
                } else if (MODE == 1) {
                    int rr = (row >> 11) * 2176 + (row & 2047);
                    ((short*)Cout)[(size_t)rr * 1024 + col] = f2b(val);
                } else {
                    ((float*)Cout)[(size_t)row * 1024 + col] = val;
                }
            }
        }
    }
}

// ---------------- per-head V transpose ----------------
__global__ __launch_bounds__(256) void k_vtrans(const short* __restrict__ vcat,
                                                short* __restrict__ vt) {
    __shared__ __align__(16) short t[64][72];
    const int kk0 = blockIdx.x * 64, h = blockIdx.y, b = blockIdx.z;
    const int tid = threadIdx.x;
    const int r = tid >> 3, c = tid & 7;
    #pragma unroll
    for (int i = 0; i < 2; ++i) {
        int row = r + i * 32;
        bf16x8 v = *(const bf16x8*)(vcat + ((size_t)(b * 2176 + kk0 + row)) * 1024 + h * 64 + c * 8);
        *(bf16x8*)(&t[row][c * 8]) = v;
    }
    __syncthreads();
    #pragma unroll
    for (int i = 0; i < 2; ++i) {
        int d = r + i * 32;
        bf16x8 outv;
        #pragma unroll
        for (int j = 0; j < 8; ++j) outv[j] = t[c * 8 + j][d];
        *(bf16x8*)(vt + ((size_t)((b * 16 + h) * 64 + d)) * 2176 + kk0 + c * 8) = outv;
    }
}

// ---------------- flash attention: 512 blocks (XCD-swizzled), 4 waves, 32 q-rows/wave ----
// K/V LDS-staged (double-buffered, global_load_lds w=16, XOR-swizzled layout),
// KVBLK=64 -> 33 steps covers 2048 keys + 64 memory slots exactly.
// Softmax: defer-max (THR=3): per-lane partial sums for l, rescale only when
// __any(lane_max > m_run + 3) -- wave-uniform branch, no per-step shfl chains.
__global__ __launch_bounds__(256) void k_attn(const short* __restrict__ qp,
                                              const short* __restrict__ kcat,
                                              const short* __restrict__ vt,
                                              const int* __restrict__ maskI,
                                              short* __restrict__ aout) {
    __shared__ __align__(16) short Ks[2][64][64];
    __shared__ __align__(16) short Vs[2][64][64];
    __shared__ __align__(16) short Pt[4][32][72];
    __shared__ float smask[2176];

    // XCD swizzle: panel g pinned to XCD bid%8 (4 panels per XCD -> 2.2MB L2-resident)
    const int bid = blockIdx.x;
    const int x = bid & 7, j = bid >> 3;
    const int g = x + 8 * (j & 3);   // panel 0..31 (h + 16*b)
    const int qt = j >> 2;           // 0..15
    const int h = g & 15, b = g >> 4;

    const int tid = threadIdx.x;
    const int w = tid >> 6, lane = tid & 63;
    const int lr = lane & 15, lg = lane >> 4;

    for (int i = tid; i < 2176; i += 256) {
        float mval;
        if (i < 2048) mval = maskI[b * 2048 + i] ? -INFINITY : 0.0f;
        else          mval = 0.0f;   // memory slots (2048..2111) never masked
        smask[i] = mval;
    }

    const short* Kb = kcat + (size_t)b * 2176 * 1024 + h * 64;   // + key*1024 + d
    const short* Vb = vt + ((size_t)(b * 16 + h) * 64) * 2176;   // + d*2176 + key

    // staging geometry: each wave stages 2x1KB segments of K and of V per step.
    // LDS dest linear; global source chunk pre-swizzled: chunk ^= (row&7).
    const int srow8 = lane >> 3;                 // row within 8-row segment
    const int schunk = (lane & 7) ^ srow8;       // swizzled 16B chunk index

    // prologue: stage step 0 into buffer 0
    #pragma unroll
    for (int jj = 0; jj < 2; ++jj) {
        int seg = w * 2 + jj;                    // 0..7
        int row = seg * 8 + srow8;               // 0..63
        gload16(Kb + (size_t)row * 1024 + schunk * 8, &Ks[0][seg * 8][0]);
        gload16(Vb + (size_t)row * 2176 + schunk * 8, &Vs[0][seg * 8][0]);
    }

    // Q fragments held in registers for the whole kernel
    const size_t qbase = ((size_t)(b * 2048 + qt * 128 + w * 32)) * 1024 + h * 64;
    bf16x8 qf[2][2];
    #pragma unroll
    for (int m = 0; m < 2; ++m)
        #pragma unroll
        for (int ks = 0; ks < 2; ++ks)
            qf[m][ks] = *(const bf16x8*)(qp + qbase + (size_t)(m * 16 + lr) * 1024 + ks * 32 + lg * 8);

    float m_run[2][4], l_part[2][4];
    f32x4 o[2][4] = {};
    #pragma unroll
    for (int m = 0; m < 2; ++m)
        #pragma unroll
        for (int r = 0; r < 4; ++r) { m_run[m][r] = -1e30f; l_part[m][r] = 0.0f; }

    __syncthreads();   // drains stage-0 + smask

    int cur = 0;
    for (int t = 0; t < 33; ++t) {
        const int key0 = t * 64;

        // stage next step into the other buffer (latency hidden under compute)
        if (t < 32) {
            const int nk0 = key0 + 64;
            #pragma unroll
            for (int jj = 0; jj < 2; ++jj) {
                int seg = w * 2 + jj;
                int row = seg * 8 + srow8;
                gload16(Kb + (size_t)(nk0 + row) * 1024 + schunk * 8, &Ks[cur ^ 1][seg * 8][0]);
                gload16(Vb + (size_t)row * 2176 + nk0 + schunk * 8, &Vs[cur ^ 1][seg * 8][0]);
            }
        }

        // S = Q K^T from LDS (swizzled, conflict-free)
        f32x4 s[2][4] = {};
        #pragma unroll
        for (int ks = 0; ks < 2; ++ks)
            #pragma unroll
            for (int n = 0; n < 4; ++n) {
                int krow = n * 16 + lr;
                int kchunk = (ks * 4 + lg) ^ (lr & 7);
                bf16x8 kf = *(const bf16x8*)((const char*)(&Ks[cur][0][0]) + krow * 128 + kchunk * 16);
                s[0][n] = __builtin_amdgcn_mfma_f32_16x16x32_bf16(qf[0][ks], kf, s[0][n], 0, 0, 0);
                s[1][n] = __builtin_amdgcn_mfma_f32_16x16x32_bf16(qf[1][ks], kf, s[1][n], 0, 0, 0);
            }

        float madd[4];
        #pragma unroll
        for (int n = 0; n < 4; ++n) madd[n] = smask[key0 + n * 16 + lr];

        // scale + mask; lane-local row max
        float lmax[2][4];
        float dmax = -1e30f;
        #pragma unroll
        for (int m = 0; m < 2; ++m)
            #pragma unroll
            for (int r = 0; r < 4; ++r) {
                float a0 = s[m][0][r] * 0.125f + madd[0];
                float a1 = s[m][1][r] * 0.125f + madd[1];
                float a2 = s[m][2][r] * 0.125f + madd[2];
                float a3 = s[m][3][r] * 0.125f + madd[3];
                s[m][0][r] = a0; s[m][1][r] = a1; s[m][2][r] = a2; s[m][3][r] = a3;
                float lm = fmaxf(fmaxf(a0, a1), fmaxf(a2, a3));
                lmax[m][r] = lm;
                dmax = fmaxf(dmax, lm - m_run[m][r]);
            }

        // defer-max: rescale only when some row's max grew past m_run + 3
        if (__any(dmax > 3.0f)) {
            #pragma unroll
            for (int m = 0; m < 2; ++m)
                #pragma unroll
                for (int r = 0; r < 4; ++r) {
                    float tm = lmax[m][r];
                    #pragma unroll
                    for (int off = 1; off < 16; off <<= 1) tm = fmaxf(tm, __shfl_xor(tm, off));
                    float mnew = fmaxf(m_run[m][r], tm);
                    float corr = __expf(m_run[m][r] - mnew);
                    m_run[m][r] = mnew;
                    l_part[m][r] *= corr;
                    #pragma unroll
                    for (int nO = 0; nO < 4; ++nO) o[m][nO][r] *= corr;
                }
        }

        // exp + per-lane partial sum + P -> LDS (wave-private, no barrier)
        #pragma unroll
        for (int m = 0; m < 2; ++m)
            #pragma unroll
            for (int n = 0; n < 4; ++n)
                #pragma unroll
                for (int r = 0; r < 4; ++r) {
                    float p = __expf(s[m][n][r] - m_run[m][r]);
                    l_part[m][r] += p;
                    Pt[w][m * 16 + lg * 4 + r][n * 16 + lr] = f2b(p);
                }

        // O += P V from LDS
        #pragma unroll
        for (int ks2 = 0; ks2 < 2; ++ks2) {
            bf16x8 pa[2];
            pa[0] = *(const bf16x8*)(&Pt[w][lr][ks2 * 32 + lg * 8]);
            pa[1] = *(const bf16x8*)(&Pt[w][16 + lr][ks2 * 32 + lg * 8]);
            #pragma unroll
            for (int nO = 0; nO < 4; ++nO) {
                int vrow = nO * 16 + lr;
                int vchunk = (ks2 * 4 + lg) ^ (lr & 7);
                bf16x8 vf = *(const bf16x8*)((const char*)(&Vs[cur][0][0]) + vrow * 128 + vchunk * 16);
                o[0][nO] = __builtin_amdgcn_mfma_f32_16x16x32_bf16(pa[0], vf, o[0][nO], 0, 0, 0);
                o[1][nO] = __builtin_amdgcn_mfma_f32_16x16x32_bf16(pa[1], vf, o[1][nO], 0, 0, 0);
            }
        }

        __syncthreads();  // next-step stage complete; all waves done with cur
        cur ^= 1;
    }

    // epilogue: reduce l across the 16 lanes of each row group, normalize, store
    #pragma unroll
    for (int m = 0; m < 2; ++m) {
        #pragma unroll
        for (int r = 0; r < 4; ++r) {
            float l = l_part[m][r];
            #pragma unroll
            for (int off = 1; off < 16; off <<= 1) l += __shfl_xor(l, off);
            float inv = 1.0f / l;
            int qrow = qt * 128 + w * 32 + m * 16 + lg * 4 + r;
            #pragma unroll
            for (int nO = 0; nO < 4; ++nO)
                aout[((size_t)(b * 2048 + qrow)) * 1024 + h * 64 + nO * 16 + lr] =
                    f2b(o[m][nO][r] * inv);
        }
    }
}

extern "C" void kernel_launch(void* const* d_in, const int* in_sizes, int n_in,
                              void* d_out, int out_size, void* d_ws, size_t ws_size,
                              hipStream_t stream) {
    const float* q  = (const float*)d_in[0];
    const float* k  = (const float*)d_in[1];
    const float* v  = (const float*)d_in[2];
    const int* mask = (const int*)d_in[3];
    const float* Wq = (const float*)d_in[4];
    const float* bq = (const float*)d_in[5];
    const float* Wk = (const float*)d_in[6];
    const float* bk = (const float*)d_in[7];
    const float* Wv = (const float*)d_in[8];
    const float* bv = (const float*)d_in[9];
    const float* Wo = (const float*)d_in[10];
    const float* bo = (const float*)d_in[11];
    const float* mk = (const float*)d_in[12];
    const float* mv = (const float*)d_in[13];

    char* ws = (char*)d_ws;
    size_t off = 0;
    auto alloc = [&](size_t bytes) {
        char* p = ws + off;
        off += (bytes + 255) & ~(size_t)255;
        return p;
    };
    short* qb   = (short*)alloc(4096ull * 1024 * 2);
    short* kb   = (short*)alloc(4096ull * 1024 * 2);
    short* vb   = (short*)alloc(4096ull * 1024 * 2);
    short* Wqb  = (short*)alloc(1024ull * 1024 * 2);
    short* Wkb  = (short*)alloc(1024ull * 1024 * 2);
    short* Wvb  = (short*)alloc(1024ull * 1024 * 2);
    short* Wob  = (short*)alloc(1024ull * 1024 * 2);
    short* qp   = (short*)alloc(4096ull * 1024 * 2);
    short* kcat = (short*)alloc(2ull * 2176 * 1024 * 2);
    short* vcat = (short*)alloc(2ull * 2176 * 1024 * 2);
    short* vtb  = (short*)alloc(2ull * 16 * 64 * 2176 * 2);
    short* aout = (short*)alloc(4096ull * 1024 * 2);

    k_cvt<<<4096, 256, 0, stream>>>(q, qb, 1048576);
    k_cvt<<<4096, 256, 0, stream>>>(k, kb, 1048576);
    k_cvt<<<4096, 256, 0, stream>>>(v, vb, 1048576);
    k_cvt<<<1024, 256, 0, stream>>>(Wq, Wqb, 262144);
    k_cvt<<<1024, 256, 0, stream>>>(Wk, Wkb, 262144);
    k_cvt<<<1024, 256, 0, stream>>>(Wv, Wvb, 262144);
    k_cvt<<<1024, 256, 0, stream>>>(Wo, Wob, 262144);
    k_aux<<<512, 256, 0, stream>>>(mk, mv, kcat, vcat, vtb);

    gemm_nt<0><<<dim3(32, 8), 256, 0, stream>>>(qb, Wqb, bq, qp);
    gemm_nt<1><<<dim3(32, 8), 256, 0, stream>>>(kb, Wkb, bk, kcat);
    gemm_nt<1><<<dim3(32, 8), 256, 0, stream>>>(vb, Wvb, bv, vcat);

    k_vtrans<<<dim3(33, 16, 2), 256, 0, stream>>>(vcat, vtb);

    k_attn<<<512, 256, 0, stream>>>(qp, kcat, vtb, mask, aout);

    gemm_nt<2><<<dim3(32, 8), 256, 0, stream>>>(aout, Wob, bo, (float*)d_out);
}

// Round 5
// 153.551 us; speedup vs baseline: 2.4606x; 1.3383x over previous
//
#include <hip/hip_runtime.h>
#include <hip/hip_bf16.h>

typedef __attribute__((ext_vector_type(8))) short bf16x8;
typedef __attribute__((ext_vector_type(4))) float f32x4;

__device__ __forceinline__ short f2b(float x) {
    __hip_bfloat16 h = __float2bfloat16(x);
    short s;
    __builtin_memcpy(&s, &h, 2);
    return s;
}

__device__ __forceinline__ void gload16(const short* g, const short* l) {
    __builtin_amdgcn_global_load_lds((const __attribute__((address_space(1))) void*)g,
                                     (__attribute__((address_space(3))) void*)l, 16, 0, 0);
}

// ---------------- fused prep: all fp32->bf16 converts + memory rows/pads ----------------
// grid (1024, 8). y=0..2: q/k/v (4 f4/thread); y=3..6: Wq/Wk/Wv/Wo (1 f4/thread);
// y=7: memory-slot rows + pads. dst bf16 buffers are CONTIGUOUS in ws starting at qb.
__global__ __launch_bounds__(256) void k_prep(const float* __restrict__ q,
                                              const float* __restrict__ k,
                                              const float* __restrict__ v,
                                              const float* __restrict__ Wq,
                                              const float* __restrict__ Wk,
                                              const float* __restrict__ Wv,
                                              const float* __restrict__ Wo,
                                              const float* __restrict__ mk,
                                              const float* __restrict__ mv,
                                              short* __restrict__ dst,    // = qb (base of bf16 region)
                                              short* __restrict__ kcat,
                                              short* __restrict__ vcat,
                                              short* __restrict__ vt) {
    const int y = blockIdx.y;
    const int i0 = blockIdx.x * 256 + threadIdx.x;
    if (y < 3) {
        const float* src = (y == 0) ? q : (y == 1) ? k : v;
        size_t base = (size_t)y * 1048576;
        #pragma unroll
        for (int it = 0; it < 4; ++it) {
            int off = i0 + it * 262144;
            float4 val = ((const float4*)src)[off];
            short4 o;
            o.x = f2b(val.x); o.y = f2b(val.y); o.z = f2b(val.z); o.w = f2b(val.w);
            ((short4*)dst)[base + off] = o;
        }
    } else if (y < 7) {
        const float* src = (y == 3) ? Wq : (y == 4) ? Wk : (y == 5) ? Wv : Wo;
        size_t base = 3145728 + (size_t)(y - 3) * 262144;
        float4 val = ((const float4*)src)[i0];
        short4 o;
        o.x = f2b(val.x); o.y = f2b(val.y); o.z = f2b(val.z); o.w = f2b(val.w);
        ((short4*)dst)[base + i0] = o;
    } else {
        if (i0 < 131072) {
            int b = i0 >> 16;
            int r = (i0 >> 10) & 63;
            int d = i0 & 1023;
            kcat[((size_t)(b * 2176 + 2048 + r)) * 1024 + d] = f2b(mk[r * 1024 + d] * 8.0f);
            vcat[((size_t)(b * 2176 + 2048 + r)) * 1024 + d] = f2b(mv[r * 1024 + d] * 8.0f);
            kcat[((size_t)(b * 2176 + 2112 + r)) * 1024 + d] = 0;
            int h = (i0 >> 12) & 15, dd = (i0 >> 6) & 63, c = i0 & 63;
            vt[((size_t)((b * 16 + h) * 64 + dd)) * 2176 + 2112 + c] = 0;
        }
    }
}

// ---------------- bf16 NT GEMM core (m97 structure): global_load_lds w=16, XOR-swizzled LDS ----
// C[r][o] = sum_k A[r][k]*W[o][k] + bias[o]. 128x128 tile, BK=32, 4 waves.
// LDS [128][32] linear (64B rows = 4x16B chunks). Both-sides swizzle:
// slot s holds global chunk s ^ ((row>>1)&3) -> fragment reads hit 8 distinct bank-quads.
template <int MODE>
__device__ __forceinline__ void gemm_core(const short* __restrict__ A,
                                          const short* __restrict__ Bw,
                                          const float* __restrict__ bias,
                                          void* __restrict__ Cout,
                                          int bm, int bn,
                                          short (*As)[32], short (*Bs)[32]) {
    const int tid = threadIdx.x;
    const int w = tid >> 6, lane = tid & 63;
    const int wm = w >> 1, wn = w & 1;
    const int lr = lane & 15, lg = lane >> 4;
    const int rseg = lane >> 2;                     // row within 16-row segment
    const int c_src = (lane & 3) ^ ((lane >> 3) & 3); // pre-swizzled global chunk
    const int slot = lg ^ ((lr >> 1) & 3);          // swizzled read slot

    const short* Ab = A + (size_t)(bm * 128) * 1024;
    const short* Bb = Bw + (size_t)(bn * 128) * 1024;

    f32x4 acc[4][4] = {};

    for (int k0 = 0; k0 < 1024; k0 += 32) {
        __syncthreads();
        #pragma unroll
        for (int jj = 0; jj < 2; ++jj) {
            int seg = w * 2 + jj;
            int row = seg * 16 + rseg;
            gload16(Ab + (size_t)row * 1024 + k0 + c_src * 8, &As[seg * 16][0]);
            gload16(Bb + (size_t)row * 1024 + k0 + c_src * 8, &Bs[seg * 16][0]);
        }
        __syncthreads();
        bf16x8 af[4], bfr[4];
        #pragma unroll
        for (int m = 0; m < 4; ++m) {
            int row = wm * 64 + m * 16 + lr;
            af[m] = *(const bf16x8*)((const char*)As + row * 64 + slot * 16);
        }
        #pragma unroll
        for (int n = 0; n < 4; ++n) {
            int row = wn * 64 + n * 16 + lr;
            bfr[n] = *(const bf16x8*)((const char*)Bs + row * 64 + slot * 16);
        }
        #pragma unroll
        for (int m = 0; m < 4; ++m)
            #pragma unroll
            for (int n = 0; n < 4; ++n)
                acc[m][n] = __builtin_amdgcn_mfma_f32_16x16x32_bf16(af[m], bfr[n], acc[m][n], 0, 0, 0);
    }

    #pragma unroll
    for (int m = 0; m < 4; ++m) {
        #pragma unroll
        for (int n = 0; n < 4; ++n) {
            int col = bn * 128 + wn * 64 + n * 16 + lr;
            float bv = bias[col];
            #pragma unroll
            for (int r = 0; r < 4; ++r) {
                int row = bm * 128 + wm * 64 + m * 16 + lg * 4 + r;
                float val = acc[m][n][r] + bv;
                if (MODE == 0) {
                    ((short*)Cout)[(size_t)row * 1024 + col] = f2b(val);
                } else if (MODE == 1) {
                    int rr = (row >> 11) * 2176 + (row & 2047);
                    ((short*)Cout)[(size_t)rr * 1024 + col] = f2b(val);
                } else {
                    ((float*)Cout)[(size_t)row * 1024 + col] = val;
                }
            }
        }
    }
}

// fused QKV projection: grid (32, 8, 3); z selects which GEMM. 768 blocks = 3/CU.
__global__ __launch_bounds__(256) void k_gemm_qkv(const short* __restrict__ qb,
                                                  const short* __restrict__ kb,
                                                  const short* __restrict__ vb,
                                                  const short* __restrict__ Wqb,
                                                  const short* __restrict__ Wkb,
                                                  const short* __restrict__ Wvb,
                                                  const float* __restrict__ bq,
                                                  const float* __restrict__ bk,
                                                  const float* __restrict__ bv,
                                                  short* __restrict__ qp,
                                                  short* __restrict__ kcat,
                                                  short* __restrict__ vcat) {
    __shared__ __align__(16) short As[128][32];
    __shared__ __align__(16) short Bs[128][32];
    const int z = blockIdx.z;
    if (z == 0)      gemm_core<0>(qb, Wqb, bq, qp,   blockIdx.x, blockIdx.y, As, Bs);
    else if (z == 1) gemm_core<1>(kb, Wkb, bk, kcat, blockIdx.x, blockIdx.y, As, Bs);
    else             gemm_core<1>(vb, Wvb, bv, vcat, blockIdx.x, blockIdx.y, As, Bs);
}

__global__ __launch_bounds__(256) void k_gemm_o(const short* __restrict__ aout,
                                                const short* __restrict__ Wob,
                                                const float* __restrict__ bo,
                                                float* __restrict__ out) {
    __shared__ __align__(16) short As[128][32];
    __shared__ __align__(16) short Bs[128][32];
    gemm_core<2>(aout, Wob, bo, out, blockIdx.x, blockIdx.y, As, Bs);
}

// ---------------- per-head V transpose ----------------
__global__ __launch_bounds__(256) void k_vtrans(const short* __restrict__ vcat,
                                                short* __restrict__ vt) {
    __shared__ __align__(16) short t[64][72];
    const int kk0 = blockIdx.x * 64, h = blockIdx.y, b = blockIdx.z;
    const int tid = threadIdx.x;
    const int r = tid >> 3, c = tid & 7;
    #pragma unroll
    for (int i = 0; i < 2; ++i) {
        int row = r + i * 32;
        bf16x8 v = *(const bf16x8*)(vcat + ((size_t)(b * 2176 + kk0 + row)) * 1024 + h * 64 + c * 8);
        *(bf16x8*)(&t[row][c * 8]) = v;
    }
    __syncthreads();
    #pragma unroll
    for (int i = 0; i < 2; ++i) {
        int d = r + i * 32;
        bf16x8 outv;
        #pragma unroll
        for (int j = 0; j < 8; ++j) outv[j] = t[c * 8 + j][d];
        *(bf16x8*)(vt + ((size_t)((b * 16 + h) * 64 + d)) * 2176 + kk0 + c * 8) = outv;
    }
}

// ---------------- flash attention (round-4 structure, unchanged) ----------------
__global__ __launch_bounds__(256) void k_attn(const short* __restrict__ qp,
                                              const short* __restrict__ kcat,
                                              const short* __restrict__ vt,
                                              const int* __restrict__ maskI,
                                              short* __restrict__ aout) {
    __shared__ __align__(16) short Ks[2][64][64];
    __shared__ __align__(16) short Vs[2][64][64];
    __shared__ __align__(16) short Pt[4][32][72];
    __shared__ float smask[2176];

    const int bid = blockIdx.x;
    const int x = bid & 7, j = bid >> 3;
    const int g = x + 8 * (j & 3);   // panel 0..31 (h + 16*b)
    const int qt = j >> 2;           // 0..15
    const int h = g & 15, b = g >> 4;

    const int tid = threadIdx.x;
    const int w = tid >> 6, lane = tid & 63;
    const int lr = lane & 15, lg = lane >> 4;

    for (int i = tid; i < 2176; i += 256) {
        float mval;
        if (i < 2048) mval = maskI[b * 2048 + i] ? -INFINITY : 0.0f;
        else          mval = 0.0f;
        smask[i] = mval;
    }

    const short* Kb = kcat + (size_t)b * 2176 * 1024 + h * 64;
    const short* Vb = vt + ((size_t)(b * 16 + h) * 64) * 2176;

    const int srow8 = lane >> 3;
    const int schunk = (lane & 7) ^ srow8;

    #pragma unroll
    for (int jj = 0; jj < 2; ++jj) {
        int seg = w * 2 + jj;
        int row = seg * 8 + srow8;
        gload16(Kb + (size_t)row * 1024 + schunk * 8, &Ks[0][seg * 8][0]);
        gload16(Vb + (size_t)row * 2176 + schunk * 8, &Vs[0][seg * 8][0]);
    }

    const size_t qbase = ((size_t)(b * 2048 + qt * 128 + w * 32)) * 1024 + h * 64;
    bf16x8 qf[2][2];
    #pragma unroll
    for (int m = 0; m < 2; ++m)
        #pragma unroll
        for (int ks = 0; ks < 2; ++ks)
            qf[m][ks] = *(const bf16x8*)(qp + qbase + (size_t)(m * 16 + lr) * 1024 + ks * 32 + lg * 8);

    float m_run[2][4], l_part[2][4];
    f32x4 o[2][4] = {};
    #pragma unroll
    for (int m = 0; m < 2; ++m)
        #pragma unroll
        for (int r = 0; r < 4; ++r) { m_run[m][r] = -1e30f; l_part[m][r] = 0.0f; }

    __syncthreads();

    int cur = 0;
    for (int t = 0; t < 33; ++t) {
        const int key0 = t * 64;

        if (t < 32) {
            const int nk0 = key0 + 64;
            #pragma unroll
            for (int jj = 0; jj < 2; ++jj) {
                int seg = w * 2 + jj;
                int row = seg * 8 + srow8;
                gload16(Kb + (size_t)(nk0 + row) * 1024 + schunk * 8, &Ks[cur ^ 1][seg * 8][0]);
                gload16(Vb + (size_t)row * 2176 + nk0 + schunk * 8, &Vs[cur ^ 1][seg * 8][0]);
            }
        }

        f32x4 s[2][4] = {};
        #pragma unroll
        for (int ks = 0; ks < 2; ++ks)
            #pragma unroll
            for (int n = 0; n < 4; ++n) {
                int krow = n * 16 + lr;
                int kchunk = (ks * 4 + lg) ^ (lr & 7);
                bf16x8 kf = *(const bf16x8*)((const char*)(&Ks[cur][0][0]) + krow * 128 + kchunk * 16);
                s[0][n] = __builtin_amdgcn_mfma_f32_16x16x32_bf16(qf[0][ks], kf, s[0][n], 0, 0, 0);
                s[1][n] = __builtin_amdgcn_mfma_f32_16x16x32_bf16(qf[1][ks], kf, s[1][n], 0, 0, 0);
            }

        float madd[4];
        #pragma unroll
        for (int n = 0; n < 4; ++n) madd[n] = smask[key0 + n * 16 + lr];

        float lmax[2][4];
        float dmax = -1e30f;
        #pragma unroll
        for (int m = 0; m < 2; ++m)
            #pragma unroll
            for (int r = 0; r < 4; ++r) {
                float a0 = s[m][0][r] * 0.125f + madd[0];
                float a1 = s[m][1][r] * 0.125f + madd[1];
                float a2 = s[m][2][r] * 0.125f + madd[2];
                float a3 = s[m][3][r] * 0.125f + madd[3];
                s[m][0][r] = a0; s[m][1][r] = a1; s[m][2][r] = a2; s[m][3][r] = a3;
                float lm = fmaxf(fmaxf(a0, a1), fmaxf(a2, a3));
                lmax[m][r] = lm;
                dmax = fmaxf(dmax, lm - m_run[m][r]);
            }

        if (__any(dmax > 3.0f)) {
            #pragma unroll
            for (int m = 0; m < 2; ++m)
                #pragma unroll
                for (int r = 0; r < 4; ++r) {
                    float tm = lmax[m][r];
                    #pragma unroll
                    for (int off = 1; off < 16; off <<= 1) tm = fmaxf(tm, __shfl_xor(tm, off));
                    float mnew = fmaxf(m_run[m][r], tm);
                    float corr = __expf(m_run[m][r] - mnew);
                    m_run[m][r] = mnew;
                    l_part[m][r] *= corr;
                    #pragma unroll
                    for (int nO = 0; nO < 4; ++nO) o[m][nO][r] *= corr;
                }
        }

        #pragma unroll
        for (int m = 0; m < 2; ++m)
            #pragma unroll
            for (int n = 0; n < 4; ++n)
                #pragma unroll
                for (int r = 0; r < 4; ++r) {
                    float p = __expf(s[m][n][r] - m_run[m][r]);
                    l_part[m][r] += p;
                    Pt[w][m * 16 + lg * 4 + r][n * 16 + lr] = f2b(p);
                }

        #pragma unroll
        for (int ks2 = 0; ks2 < 2; ++ks2) {
            bf16x8 pa[2];
            pa[0] = *(const bf16x8*)(&Pt[w][lr][ks2 * 32 + lg * 8]);
            pa[1] = *(const bf16x8*)(&Pt[w][16 + lr][ks2 * 32 + lg * 8]);
            #pragma unroll
            for (int nO = 0; nO < 4; ++nO) {
                int vrow = nO * 16 + lr;
                int vchunk = (ks2 * 4 + lg) ^ (lr & 7);
                bf16x8 vf = *(const bf16x8*)((const char*)(&Vs[cur][0][0]) + vrow * 128 + vchunk * 16);
                o[0][nO] = __builtin_amdgcn_mfma_f32_16x16x32_bf16(pa[0], vf, o[0][nO], 0, 0, 0);
                o[1][nO] = __builtin_amdgcn_mfma_f32_16x16x32_bf16(pa[1], vf, o[1][nO], 0, 0, 0);
            }
        }

        __syncthreads();
        cur ^= 1;
    }

    #pragma unroll
    for (int m = 0; m < 2; ++m) {
        #pragma unroll
        for (int r = 0; r < 4; ++r) {
            float l = l_part[m][r];
            #pragma unroll
            for (int off = 1; off < 16; off <<= 1) l += __shfl_xor(l, off);
            float inv = 1.0f / l;
            int qrow = qt * 128 + w * 32 + m * 16 + lg * 4 + r;
            #pragma unroll
            for (int nO = 0; nO < 4; ++nO)
                aout[((size_t)(b * 2048 + qrow)) * 1024 + h * 64 + nO * 16 + lr] =
                    f2b(o[m][nO][r] * inv);
        }
    }
}

extern "C" void kernel_launch(void* const* d_in, const int* in_sizes, int n_in,
                              void* d_out, int out_size, void* d_ws, size_t ws_size,
                              hipStream_t stream) {
    const float* q  = (const float*)d_in[0];
    const float* k  = (const float*)d_in[1];
    const float* v  = (const float*)d_in[2];
    const int* mask = (const int*)d_in[3];
    const float* Wq = (const float*)d_in[4];
    const float* bq = (const float*)d_in[5];
    const float* Wk = (const float*)d_in[6];
    const float* bk = (const float*)d_in[7];
    const float* Wv = (const float*)d_in[8];
    const float* bv = (const float*)d_in[9];
    const float* Wo = (const float*)d_in[10];
    const float* bo = (const float*)d_in[11];
    const float* mk = (const float*)d_in[12];
    const float* mv = (const float*)d_in[13];

    char* ws = (char*)d_ws;
    size_t off = 0;
    auto alloc = [&](size_t bytes) {
        char* p = ws + off;
        off += (bytes + 255) & ~(size_t)255;
        return p;
    };
    // NOTE: qb..Wob must stay contiguous in this exact order (k_prep writes them
    // as one flat region starting at qb).
    short* qb   = (short*)alloc(4096ull * 1024 * 2);
    short* kb   = (short*)alloc(4096ull * 1024 * 2);
    short* vb   = (short*)alloc(4096ull * 1024 * 2);
    short* Wqb  = (short*)alloc(1024ull * 1024 * 2);
    short* Wkb  = (short*)alloc(1024ull * 1024 * 2);
    short* Wvb  = (short*)alloc(1024ull * 1024 * 2);
    short* Wob  = (short*)alloc(1024ull * 1024 * 2);
    short* qp   = (short*)alloc(4096ull * 1024 * 2);
    short* kcat = (short*)alloc(2ull * 2176 * 1024 * 2);
    short* vcat = (short*)alloc(2ull * 2176 * 1024 * 2);
    short* vtb  = (short*)alloc(2ull * 16 * 64 * 2176 * 2);
    short* aout = (short*)alloc(4096ull * 1024 * 2);

    k_prep<<<dim3(1024, 8), 256, 0, stream>>>(q, k, v, Wq, Wk, Wv, Wo, mk, mv,
                                              qb, kcat, vcat, vtb);

    k_gemm_qkv<<<dim3(32, 8, 3), 256, 0, stream>>>(qb, kb, vb, Wqb, Wkb, Wvb,
                                                   bq, bk, bv, qp, kcat, vcat);

    k_vtrans<<<dim3(33, 16, 2), 256, 0, stream>>>(vcat, vtb);

    k_attn<<<512, 256, 0, stream>>>(qp, kcat, vtb, mask, aout);

    k_gemm_o<<<dim3(32, 8), 256, 0, stream>>>(aout, Wob, bo, (float*)d_out);
}

// Round 7
// 141.383 us; speedup vs baseline: 2.6724x; 1.0861x over previous
//
#include <hip/hip_runtime.h>
#include <hip/hip_bf16.h>

typedef __attribute__((ext_vector_type(8))) short bf16x8;
typedef __attribute__((ext_vector_type(4))) float f32x4;

__device__ __forceinline__ short f2b(float x) {
    __hip_bfloat16 h = __float2bfloat16(x);
    short s;
    __builtin_memcpy(&s, &h, 2);
    return s;
}

__device__ __forceinline__ void gload16(const short* g, const short* l) {
    __builtin_amdgcn_global_load_lds((const __attribute__((address_space(1))) void*)g,
                                     (__attribute__((address_space(3))) void*)l, 16, 0, 0);
}

// ---------------- fused prep: all fp32->bf16 converts + memory rows/pads ----------------
__global__ __launch_bounds__(256) void k_prep(const float* __restrict__ q,
                                              const float* __restrict__ k,
                                              const float* __restrict__ v,
                                              const float* __restrict__ Wq,
                                              const float* __restrict__ Wk,
                                              const float* __restrict__ Wv,
                                              const float* __restrict__ Wo,
                                              const float* __restrict__ mk,
                                              const float* __restrict__ mv,
                                              short* __restrict__ dst,    // = qb (base of bf16 region)
                                              short* __restrict__ kcat,
                                              short* __restrict__ vcat,
                                              short* __restrict__ vt) {
    const int y = blockIdx.y;
    const int i0 = blockIdx.x * 256 + threadIdx.x;
    if (y < 3) {
        const float* src = (y == 0) ? q : (y == 1) ? k : v;
        size_t base = (size_t)y * 1048576;
        #pragma unroll
        for (int it = 0; it < 4; ++it) {
            int off = i0 + it * 262144;
            float4 val = ((const float4*)src)[off];
            short4 o;
            o.x = f2b(val.x); o.y = f2b(val.y); o.z = f2b(val.z); o.w = f2b(val.w);
            ((short4*)dst)[base + off] = o;
        }
    } else if (y < 7) {
        const float* src = (y == 3) ? Wq : (y == 4) ? Wk : (y == 5) ? Wv : Wo;
        size_t base = 3145728 + (size_t)(y - 3) * 262144;
        float4 val = ((const float4*)src)[i0];
        short4 o;
        o.x = f2b(val.x); o.y = f2b(val.y); o.z = f2b(val.z); o.w = f2b(val.w);
        ((short4*)dst)[base + i0] = o;
    } else {
        if (i0 < 131072) {
            int b = i0 >> 16;
            int r = (i0 >> 10) & 63;
            int d = i0 & 1023;
            kcat[((size_t)(b * 2176 + 2048 + r)) * 1024 + d] = f2b(mk[r * 1024 + d] * 8.0f);
            vcat[((size_t)(b * 2176 + 2048 + r)) * 1024 + d] = f2b(mv[r * 1024 + d] * 8.0f);
            kcat[((size_t)(b * 2176 + 2112 + r)) * 1024 + d] = 0;
            int h = (i0 >> 12) & 15, dd = (i0 >> 6) & 63, c = i0 & 63;
            vt[((size_t)((b * 16 + h) * 64 + dd)) * 2176 + 2112 + c] = 0;
        }
    }
}

// ---------------- bf16 NT GEMM core (m97 structure) ----------------
template <int MODE>
__device__ __forceinline__ void gemm_core(const short* __restrict__ A,
                                          const short* __restrict__ Bw,
                                          const float* __restrict__ bias,
                                          void* __restrict__ Cout,
                                          int bm, int bn,
                                          short (*As)[32], short (*Bs)[32]) {
    const int tid = threadIdx.x;
    const int w = tid >> 6, lane = tid & 63;
    const int wm = w >> 1, wn = w & 1;
    const int lr = lane & 15, lg = lane >> 4;
    const int rseg = lane >> 2;
    const int c_src = (lane & 3) ^ ((lane >> 3) & 3);
    const int slot = lg ^ ((lr >> 1) & 3);

    const short* Ab = A + (size_t)(bm * 128) * 1024;
    const short* Bb = Bw + (size_t)(bn * 128) * 1024;

    f32x4 acc[4][4] = {};

    for (int k0 = 0; k0 < 1024; k0 += 32) {
        __syncthreads();
        #pragma unroll
        for (int jj = 0; jj < 2; ++jj) {
            int seg = w * 2 + jj;
            int row = seg * 16 + rseg;
            gload16(Ab + (size_t)row * 1024 + k0 + c_src * 8, &As[seg * 16][0]);
            gload16(Bb + (size_t)row * 1024 + k0 + c_src * 8, &Bs[seg * 16][0]);
        }
        __syncthreads();
        bf16x8 af[4], bfr[4];
        #pragma unroll
        for (int m = 0; m < 4; ++m) {
            int row = wm * 64 + m * 16 + lr;
            af[m] = *(const bf16x8*)((const char*)As + row * 64 + slot * 16);
        }
        #pragma unroll
        for (int n = 0; n < 4; ++n) {
            int row = wn * 64 + n * 16 + lr;
            bfr[n] = *(const bf16x8*)((const char*)Bs + row * 64 + slot * 16);
        }
        #pragma unroll
        for (int m = 0; m < 4; ++m)
            #pragma unroll
            for (int n = 0; n < 4; ++n)
                acc[m][n] = __builtin_amdgcn_mfma_f32_16x16x32_bf16(af[m], bfr[n], acc[m][n], 0, 0, 0);
    }

    #pragma unroll
    for (int m = 0; m < 4; ++m) {
        #pragma unroll
        for (int n = 0; n < 4; ++n) {
            int col = bn * 128 + wn * 64 + n * 16 + lr;
            float bv = bias[col];
            #pragma unroll
            for (int r = 0; r < 4; ++r) {
                int row = bm * 128 + wm * 64 + m * 16 + lg * 4 + r;
                float val = acc[m][n][r] + bv;
                if (MODE == 0) {
                    ((short*)Cout)[(size_t)row * 1024 + col] = f2b(val);
                } else if (MODE == 1) {
                    int rr = (row >> 11) * 2176 + (row & 2047);
                    ((short*)Cout)[(size_t)rr * 1024 + col] = f2b(val);
                } else {
                    ((float*)Cout)[(size_t)row * 1024 + col] = val;
                }
            }
        }
    }
}

__global__ __launch_bounds__(256) void k_gemm_qkv(const short* __restrict__ qb,
                                                  const short* __restrict__ kb,
                                                  const short* __restrict__ vb,
                                                  const short* __restrict__ Wqb,
                                                  const short* __restrict__ Wkb,
                                                  const short* __restrict__ Wvb,
                                                  const float* __restrict__ bq,
                                                  const float* __restrict__ bk,
                                                  const float* __restrict__ bv,
                                                  short* __restrict__ qp,
                                                  short* __restrict__ kcat,
                                                  short* __restrict__ vcat) {
    __shared__ __align__(16) short As[128][32];
    __shared__ __align__(16) short Bs[128][32];
    const int z = blockIdx.z;
    if (z == 0)      gemm_core<0>(qb, Wqb, bq, qp,   blockIdx.x, blockIdx.y, As, Bs);
    else if (z == 1) gemm_core<1>(kb, Wkb, bk, kcat, blockIdx.x, blockIdx.y, As, Bs);
    else             gemm_core<1>(vb, Wvb, bv, vcat, blockIdx.x, blockIdx.y, As, Bs);
}

__global__ __launch_bounds__(256) void k_gemm_o(const short* __restrict__ aout,
                                                const short* __restrict__ Wob,
                                                const float* __restrict__ bo,
                                                float* __restrict__ out) {
    __shared__ __align__(16) short As[128][32];
    __shared__ __align__(16) short Bs[128][32];
    gemm_core<2>(aout, Wob, bo, out, blockIdx.x, blockIdx.y, As, Bs);
}

// ---------------- per-head V transpose ----------------
__global__ __launch_bounds__(256) void k_vtrans(const short* __restrict__ vcat,
                                                short* __restrict__ vt) {
    __shared__ __align__(16) short t[64][72];
    const int kk0 = blockIdx.x * 64, h = blockIdx.y, b = blockIdx.z;
    const int tid = threadIdx.x;
    const int r = tid >> 3, c = tid & 7;
    #pragma unroll
    for (int i = 0; i < 2; ++i) {
        int row = r + i * 32;
        bf16x8 v = *(const bf16x8*)(vcat + ((size_t)(b * 2176 + kk0 + row)) * 1024 + h * 64 + c * 8);
        *(bf16x8*)(&t[row][c * 8]) = v;
    }
    __syncthreads();
    #pragma unroll
    for (int i = 0; i < 2; ++i) {
        int d = r + i * 32;
        bf16x8 outv;
        #pragma unroll
        for (int j = 0; j < 8; ++j) outv[j] = t[c * 8 + j][d];
        *(bf16x8*)(vt + ((size_t)((b * 16 + h) * 64 + d)) * 2176 + kk0 + c * 8) = outv;
    }
}

// ---------------- flash attention: 512 blocks (XCD-swizzled), 8 waves x 16 q-rows ----
// Swapped QK^T: s = mfma(K, Q) -> lane holds P[q=lr][key=n*16+lg*4+r].
// P->LDS via __builtin_memcpy ONLY (TBAA-safe: round-6's uint2-store/bf16x8-load
// mixed-type aliasing on the unfenced wave-private Pt RAW was UB) + explicit
// lgkmcnt fence before PV reads.
__global__ __launch_bounds__(512) void k_attn(const short* __restrict__ qp,
                                              const short* __restrict__ kcat,
                                              const short* __restrict__ vt,
                                              const int* __restrict__ maskI,
                                              short* __restrict__ aout) {
    __shared__ __align__(16) short Ks[2][64][64];
    __shared__ __align__(16) short Vs[2][64][64];
    __shared__ __align__(16) short Pt[8][16][72];
    __shared__ float smask[2176];

    const int bid = blockIdx.x;
    const int x = bid & 7, j = bid >> 3;
    const int g = x + 8 * (j & 3);   // panel 0..31 (h + 16*b)
    const int qt = j >> 2;           // 0..15
    const int h = g & 15, b = g >> 4;

    const int tid = threadIdx.x;
    const int w = tid >> 6, lane = tid & 63;
    const int lr = lane & 15, lg = lane >> 4;

    for (int i = tid; i < 2176; i += 512) {
        float mval;
        if (i < 2048) mval = maskI[b * 2048 + i] ? -INFINITY : 0.0f;
        else          mval = 0.0f;   // memory slots never masked
        smask[i] = mval;
    }

    const short* Kb = kcat + (size_t)b * 2176 * 1024 + h * 64;
    const short* Vb = vt + ((size_t)(b * 16 + h) * 64) * 2176;

    const int srow8 = lane >> 3;
    const int schunk = (lane & 7) ^ srow8;   // pre-swizzled global chunk

    // stage tile 0: wave w stages K rows w*8..w*8+7 and V (d-)rows w*8..w*8+7
    {
        int row = w * 8 + srow8;
        gload16(Kb + (size_t)row * 1024 + schunk * 8, &Ks[0][w * 8][0]);
        gload16(Vb + (size_t)row * 2176 + schunk * 8, &Vs[0][w * 8][0]);
    }

    // Q fragments (16 rows per wave), second-operand layout
    const size_t qbase = ((size_t)(b * 2048 + qt * 128 + w * 16)) * 1024 + h * 64;
    bf16x8 qf[2];
    #pragma unroll
    for (int ks = 0; ks < 2; ++ks)
        qf[ks] = *(const bf16x8*)(qp + qbase + (size_t)lr * 1024 + ks * 32 + lg * 8);

    float m_run = -1e30f, l_part = 0.0f;
    f32x4 o[4] = {};

    __syncthreads();   // stage-0 + smask

    int cur = 0;
    for (int t = 0; t < 33; ++t) {
        const int key0 = t * 64;

        if (t < 32) {
            const int nk0 = key0 + 64;
            int row = w * 8 + srow8;
            gload16(Kb + (size_t)(nk0 + row) * 1024 + schunk * 8, &Ks[cur ^ 1][w * 8][0]);
            gload16(Vb + (size_t)row * 2176 + nk0 + schunk * 8, &Vs[cur ^ 1][w * 8][0]);
        }

        // S^T = K Q^T : lane holds P[q=lr][key = n*16 + lg*4 + r]
        f32x4 s[4] = {};
        #pragma unroll
        for (int ks = 0; ks < 2; ++ks)
            #pragma unroll
            for (int n = 0; n < 4; ++n) {
                int krow = n * 16 + lr;
                int kchunk = (ks * 4 + lg) ^ (lr & 7);
                bf16x8 kf = *(const bf16x8*)((const char*)(&Ks[cur][0][0]) + krow * 128 + kchunk * 16);
                s[n] = __builtin_amdgcn_mfma_f32_16x16x32_bf16(kf, qf[ks], s[n], 0, 0, 0);
            }

        // scale + mask (this lane's 4 keys per n are consecutive)
        float lm = -1e30f;
        #pragma unroll
        for (int n = 0; n < 4; ++n) {
            float4 mq = *(const float4*)(&smask[key0 + n * 16 + lg * 4]);
            s[n][0] = s[n][0] * 0.125f + mq.x;
            s[n][1] = s[n][1] * 0.125f + mq.y;
            s[n][2] = s[n][2] * 0.125f + mq.z;
            s[n][3] = s[n][3] * 0.125f + mq.w;
            lm = fmaxf(lm, fmaxf(fmaxf(s[n][0], s[n][1]), fmaxf(s[n][2], s[n][3])));
        }

        // defer-max: rescale only when some lane's partial max grew past m_run + 3
        if (__any(lm - m_run > 3.0f)) {
            float tm = lm;
            tm = fmaxf(tm, __shfl_xor(tm, 16));
            tm = fmaxf(tm, __shfl_xor(tm, 32));   // row max (uniform across lg copies)
            float mnew = fmaxf(m_run, tm);
            float corr = __expf(m_run - mnew);
            m_run = mnew;
            l_part *= corr;
            // broadcast corr from q-domain (q=lr) to o-domain (q=lg*4+r)
            #pragma unroll
            for (int r = 0; r < 4; ++r) {
                float cb = __shfl(corr, 20 * lg + r);
                #pragma unroll
                for (int nO = 0; nO < 4; ++nO) o[nO][r] *= cb;
            }
        }

        // exp + per-lane partial sum + packed P -> LDS (wave-private rows)
        #pragma unroll
        for (int n = 0; n < 4; ++n) {
            float p0 = __expf(s[n][0] - m_run);
            float p1 = __expf(s[n][1] - m_run);
            float p2 = __expf(s[n][2] - m_run);
            float p3 = __expf(s[n][3] - m_run);
            l_part += (p0 + p1) + (p2 + p3);
            unsigned pk[2];
            pk[0] = (unsigned)(unsigned short)f2b(p0) | ((unsigned)(unsigned short)f2b(p1) << 16);
            pk[1] = (unsigned)(unsigned short)f2b(p2) | ((unsigned)(unsigned short)f2b(p3) << 16);
            __builtin_memcpy((char*)(&Pt[w][0][0]) + lr * 144 + n * 32 + lg * 8, pk, 8);
        }

        // order P ds_writes before PV ds_reads regardless of aliasing analysis
        asm volatile("s_waitcnt lgkmcnt(0)" ::: "memory");
        __builtin_amdgcn_sched_barrier(0);

        // O += P V
        #pragma unroll
        for (int ks2 = 0; ks2 < 2; ++ks2) {
            bf16x8 pa;
            __builtin_memcpy(&pa, (const char*)(&Pt[w][0][0]) + lr * 144 + ks2 * 64 + lg * 16, 16);
            #pragma unroll
            for (int nO = 0; nO < 4; ++nO) {
                int vrow = nO * 16 + lr;
                int vchunk = (ks2 * 4 + lg) ^ (lr & 7);
                bf16x8 vf = *(const bf16x8*)((const char*)(&Vs[cur][0][0]) + vrow * 128 + vchunk * 16);
                o[nO] = __builtin_amdgcn_mfma_f32_16x16x32_bf16(pa, vf, o[nO], 0, 0, 0);
            }
        }

        __syncthreads();
        cur ^= 1;
    }

    // final row-sum reduce (lg dim), normalize, store
    float l = l_part;
    l += __shfl_xor(l, 16);
    l += __shfl_xor(l, 32);
    float inv = 1.0f / l;
    #pragma unroll
    for (int r = 0; r < 4; ++r) {
        float ib = __shfl(inv, 20 * lg + r);
        int qrow = qt * 128 + w * 16 + lg * 4 + r;
        #pragma unroll
        for (int nO = 0; nO < 4; ++nO)
            aout[((size_t)(b * 2048 + qrow)) * 1024 + h * 64 + nO * 16 + lr] =
                f2b(o[nO][r] * ib);
    }
}

extern "C" void kernel_launch(void* const* d_in, const int* in_sizes, int n_in,
                              void* d_out, int out_size, void* d_ws, size_t ws_size,
                              hipStream_t stream) {
    const float* q  = (const float*)d_in[0];
    const float* k  = (const float*)d_in[1];
    const float* v  = (const float*)d_in[2];
    const int* mask = (const int*)d_in[3];
    const float* Wq = (const float*)d_in[4];
    const float* bq = (const float*)d_in[5];
    const float* Wk = (const float*)d_in[6];
    const float* bk = (const float*)d_in[7];
    const float* Wv = (const float*)d_in[8];
    const float* bv = (const float*)d_in[9];
    const float* Wo = (const float*)d_in[10];
    const float* bo = (const float*)d_in[11];
    const float* mk = (const float*)d_in[12];
    const float* mv = (const float*)d_in[13];

    char* ws = (char*)d_ws;
    size_t off = 0;
    auto alloc = [&](size_t bytes) {
        char* p = ws + off;
        off += (bytes + 255) & ~(size_t)255;
        return p;
    };
    // NOTE: qb..Wob must stay contiguous in this exact order (k_prep writes them
    // as one flat region starting at qb).
    short* qb   = (short*)alloc(4096ull * 1024 * 2);
    short* kb   = (short*)alloc(4096ull * 1024 * 2);
    short* vb   = (short*)alloc(4096ull * 1024 * 2);
    short* Wqb  = (short*)alloc(1024ull * 1024 * 2);
    short* Wkb  = (short*)alloc(1024ull * 1024 * 2);
    short* Wvb  = (short*)alloc(1024ull * 1024 * 2);
    short* Wob  = (short*)alloc(1024ull * 1024 * 2);
    short* qp   = (short*)alloc(4096ull * 1024 * 2);
    short* kcat = (short*)alloc(2ull * 2176 * 1024 * 2);
    short* vcat = (short*)alloc(2ull * 2176 * 1024 * 2);
    short* vtb  = (short*)alloc(2ull * 16 * 64 * 2176 * 2);
    short* aout = (short*)alloc(4096ull * 1024 * 2);

    k_prep<<<dim3(1024, 8), 256, 0, stream>>>(q, k, v, Wq, Wk, Wv, Wo, mk, mv,
                                              qb, kcat, vcat, vtb);

    k_gemm_qkv<<<dim3(32, 8, 3), 256, 0, stream>>>(qb, kb, vb, Wqb, Wkb, Wvb,
                                                   bq, bk, bv, qp, kcat, vcat);

    k_vtrans<<<dim3(33, 16, 2), 256, 0, stream>>>(vcat, vtb);

    k_attn<<<512, 512, 0, stream>>>(qp, kcat, vtb, mask, aout);

    k_gemm_o<<<dim3(32, 8), 256, 0, stream>>>(aout, Wob, bo, (float*)d_out);
}